// Round 4
// baseline (146.857 us; speedup 1.0000x reference)
//
#include <hip/hip_runtime.h>
#include <math.h>

#define N_NODES 100000
#define N_EDGES 1600000

#define BK_LOG 7
#define BKW 128                               // nodes per bucket
#define NBK ((N_NODES + BKW - 1) / BKW)       // 782 buckets
#define GS 400                                // scatter blocks
#define EPS (N_EDGES / GS)                    // 4000 edges per block (exact)
#define EPS4 (EPS / 4)                        // 1000 int4 per block
#define SR ((EPS4 + 255) / 256)               // 4 load rounds

#define CH 28          // words per (block,bucket) chunk: [cnt, rec0..rec26]
#define CAPC (CH - 1)  // 27 records; Poisson(5.1) -> P(overflow) ~ 3e-5 total

#define NT_BLOCKS ((N_NODES + 63) / 64)       // 1563 nodeT blocks (64 nodes each)

typedef int i32x4 __attribute__((ext_vector_type(4)));

// ---------------------------------------------------------------------------
// K1 (mixed grid): blocks [0, GS) scatter edges into DETERMINISTIC per-
// (block,bucket) chunks -- no global cursor, no memset, no second pass.
// Chunk for (g,b) lives at ework[(b*GS+g)*CH]: word0 = count, words 1..27 =
// packed records ((dst&127)<<17 | src). Rank from the block-private LDS
// histogram IS the final slot (single writer per chunk). Bucket-major layout
// makes K2's read contiguous per bucket (44.8 KB run).
// Blocks [GS, ...) compute nodeT = feat @ Q + c, Q = W_in @ P, c = b_in @ P,
// P = [W_u, W_out[:,0], W_out[:,1], W_v] (hidden layer collapsed).
// ---------------------------------------------------------------------------
__global__ __launch_bounds__(256) void prep_kernel(
    const float* __restrict__ feat,
    const float* __restrict__ W_in,
    const float* __restrict__ b_in,
    const float* __restrict__ W_edge,
    const float* __restrict__ W_out,
    const int*   __restrict__ src,
    const int*   __restrict__ dst,
    int* __restrict__ ework,
    float4* __restrict__ nodeT)
{
    const int tid = threadIdx.x;

    // ---------------- scatter blocks ----------------
    if ((int)blockIdx.x < GS) {
        __shared__ int hist[NBK];
        for (int i = tid; i < NBK; i += 256) hist[i] = 0;
        __syncthreads();

        const int4* src4 = (const int4*)src;
        const int4* dst4 = (const int4*)dst;
        const int   b40  = (int)blockIdx.x * EPS4;
        const int   g    = (int)blockIdx.x;

        #pragma unroll
        for (int j = 0; j < SR; ++j) {
            const int o4 = j * 256 + tid;
            if (o4 < EPS4) {
                const int4 d4 = dst4[b40 + o4];
                const int4 s4 = src4[b40 + o4];
                const int dv[4] = {d4.x, d4.y, d4.z, d4.w};
                const int sv[4] = {s4.x, s4.y, s4.z, s4.w};
                #pragma unroll
                for (int u = 0; u < 4; ++u) {
                    const int d = dv[u];
                    const int b = d >> BK_LOG;
                    const int r = atomicAdd(&hist[b], 1);
                    if (r < CAPC)
                        ework[(b * GS + g) * CH + 1 + r] =
                            ((d & (BKW - 1)) << 17) | sv[u];
                }
            }
        }
        __syncthreads();

        // write chunk headers (count); every header is written -> poisoned
        // slots beyond cnt are never interpreted
        for (int i = tid; i < NBK; i += 256)
            ework[(i * GS + g) * CH] = min(hist[i], CAPC);
        return;
    }

    // ---------------- nodeT blocks ----------------
    __shared__ float sP[64 * 4];   // P[m][j] row-major
    __shared__ float sQ[64 * 4];   // Q[k][j] row-major, 16B rows
    __shared__ float sc[4];

    if (tid < 64) {
        sP[tid * 4 + 0] = W_edge[tid];            // W_u
        sP[tid * 4 + 1] = W_out[tid * 2 + 0];     // W_out[:,0]
        sP[tid * 4 + 2] = W_out[tid * 2 + 1];     // W_out[:,1]
        sP[tid * 4 + 3] = W_edge[64 + tid];       // W_v
    }
    __syncthreads();

    {   // Q[k][j] = sum_m W_in[k][m] * P[m][j]
        const int k = tid >> 2, j = tid & 3;
        float q = 0.f;
        for (int m = 0; m < 64; ++m) q += W_in[k * 64 + m] * sP[m * 4 + j];
        sQ[k * 4 + j] = q;
        if (tid < 4) {
            float cc = 0.f;
            for (int m = 0; m < 64; ++m) cc += b_in[m] * sP[m * 4 + tid];
            sc[tid] = cc;
        }
    }
    __syncthreads();

    const int lane = tid & 63;
    const int wv   = tid >> 6;
    const int n    = ((int)blockIdx.x - GS) * 64 + wv * 16 + (lane >> 2);
    const int ks   = (lane & 3) << 4;                           // 16 k's/lane

    float p0 = 0.f, p1 = 0.f, p2 = 0.f, p3 = 0.f;
    if (n < N_NODES) {
        const float* fr = feat + (size_t)n * 64 + ks;
        #pragma unroll
        for (int i4 = 0; i4 < 4; ++i4) {
            const float4 f = *(const float4*)(fr + i4 * 4);
            const float fv[4] = {f.x, f.y, f.z, f.w};
            #pragma unroll
            for (int u = 0; u < 4; ++u) {
                const float4 q = *(const float4*)&sQ[(ks + i4 * 4 + u) * 4];
                p0 += fv[u] * q.x;
                p1 += fv[u] * q.y;
                p2 += fv[u] * q.z;
                p3 += fv[u] * q.w;
            }
        }
    }
    #pragma unroll
    for (int off = 1; off <= 2; off <<= 1) {
        p0 += __shfl_xor(p0, off);
        p1 += __shfl_xor(p1, off);
        p2 += __shfl_xor(p2, off);
        p3 += __shfl_xor(p3, off);
    }
    if (n < N_NODES && (lane & 3) == 0)
        nodeT[n] = make_float4(p0 + sc[0], p1 + sc[1], p2 + sc[2], p3 + sc[3]);
}

// ---------------------------------------------------------------------------
// K2: unsorted aggregation via LDS fp32 atomics (ds_add_f32, per-CU -- NOT
// the cross-XCD global path). One block (512 thr) per 128-node bucket.
// Thread t < GS owns chunk t: 7 nontemporal int4 loads from a contiguous
// 44.8 KB bucket run (consecutive lanes -> consecutive lines), then per
// record: gather nodeT[src] (16B, L2-resident), sigmoid, 3 LDS atomics
// (m0, m1, count). Finalize fused. No global atomics anywhere.
// ---------------------------------------------------------------------------
__global__ __launch_bounds__(512) void agg_kernel(
    const int* __restrict__ ework,
    const float4* __restrict__ nodeT,
    const float* __restrict__ b_edge,
    const float* __restrict__ b_out,
    float2* __restrict__ out)
{
    __shared__ float4 sT[BKW];   // .w pre-biased with b_edge; .y/.z fallback
    __shared__ float  aM0[BKW];
    __shared__ float  aM1[BKW];
    __shared__ int    aC[BKW];

    const int b   = blockIdx.x;
    const int tid = threadIdx.x;

    if (tid < BKW) {
        const int n = b * BKW + tid;
        float4 t = make_float4(0.f, 0.f, 0.f, 0.f);
        if (n < N_NODES) t = nodeT[n];
        t.w += b_edge[0];
        sT[tid] = t;
        aM0[tid] = 0.f;
        aM1[tid] = 0.f;
        aC[tid]  = 0;
    }
    __syncthreads();

    if (tid < GS) {
        const i32x4* cp = (const i32x4*)(ework + ((size_t)b * GS + tid) * CH);
        i32x4 v[7];
        #pragma unroll
        for (int j = 0; j < 7; ++j) v[j] = __builtin_nontemporal_load(cp + j);
        const int cnt = min(v[0].x, CAPC);

        #pragma unroll
        for (int j = 0; j < 7; ++j) {
            const int ve[4] = {v[j].x, v[j].y, v[j].z, v[j].w};
            #pragma unroll
            for (int u = 0; u < 4; ++u) {
                const int w = j * 4 + u;           // word index in chunk
                if (w >= 1 && w <= cnt) {          // record idx = w-1 < cnt
                    const int    rec = ve[u];
                    const int    l   = rec >> 17;
                    const int    s   = rec & 0x1FFFF;
                    const float4 t   = nodeT[s];
                    const float  wg  = 1.0f / (1.0f + __expf(-(t.x + sT[l].w)));
                    atomicAdd(&aM0[l], wg * t.y);
                    atomicAdd(&aM1[l], wg * t.z);
                    atomicAdd(&aC[l], 1);
                }
            }
        }
    }
    __syncthreads();

    if (tid < BKW) {
        const int n = b * BKW + tid;
        if (n < N_NODES) {
            const bool has = aC[tid] > 0;
            out[n] = make_float2((has ? aM0[tid] : sT[tid].y) + b_out[0],
                                 (has ? aM1[tid] : sT[tid].z) + b_out[1]);
        }
    }
}

// ---------------------------------------------------------------------------
extern "C" void kernel_launch(void* const* d_in, const int* in_sizes, int n_in,
                              void* d_out, int out_size, void* d_ws, size_t ws_size,
                              hipStream_t stream) {
    const float* feat   = (const float*)d_in[0];
    const int*   src    = (const int*)d_in[1];
    const int*   dst    = (const int*)d_in[2];
    const float* W_in   = (const float*)d_in[3];
    const float* b_in   = (const float*)d_in[4];
    const float* W_edge = (const float*)d_in[5];
    const float* b_edge = (const float*)d_in[6];
    const float* W_out  = (const float*)d_in[7];
    const float* b_out  = (const float*)d_in[8];
    float2* out = (float2*)d_out;

    // workspace: nodeT (1.6 MB) | ework chunks (NBK*GS*CH ints = 35 MB)
    float4* nodeT = (float4*)d_ws;
    int*    ework = (int*)(nodeT + N_NODES);

    prep_kernel<<<GS + NT_BLOCKS, 256, 0, stream>>>(
        feat, W_in, b_in, W_edge, W_out, src, dst, ework, nodeT);
    agg_kernel<<<NBK, 512, 0, stream>>>(
        ework, nodeT, b_edge, b_out, out);
}

// Round 6
// 142.206 us; speedup vs baseline: 1.0327x; 1.0327x over previous
//
#include <hip/hip_runtime.h>
#include <math.h>

#define N_NODES 100000
#define N_EDGES 1600000

#define BK_LOG 7
#define BKW 128                               // nodes per bucket
#define NBK ((N_NODES + BKW - 1) / BKW)       // 782 buckets
#define CAPB 2688   // per-bucket capacity; mean 2046, sigma~45 -> +14 sigma
#define UNS4 3      // int4 load rounds in agg (3*256*4 = 3072 >= CAPB)

#define GS 400                                // scatter blocks (grid-first)
#define EPS (N_EDGES / GS)                    // 4000 edges per block (exact)
#define EPS4 (EPS / 4)                        // 1000 int4 per block

#define NT_BLOCKS ((N_NODES + 63) / 64)       // 1563 nodeT blocks (64 nodes each)

// ---------------------------------------------------------------------------
// K1 (mixed grid) -- identical to round-1 best: blocks [0, GS) scatter edges
// into fixed-capacity 128-node-bucket regions (register-staged single pass,
// LDS rank, ONE global cursor atomic per non-empty (block,bucket)).
// Blocks [GS, ...) compute nodeT = feat @ Q + c, Q = W_in @ P, c = b_in @ P,
// P = [W_u, W_out[:,0], W_out[:,1], W_v] (hidden layer collapsed).
// Record: ((dst&127)<<17 | src), src < 2^17.
// ---------------------------------------------------------------------------
__global__ __launch_bounds__(256) void prep_kernel(
    const float* __restrict__ feat,
    const float* __restrict__ W_in,
    const float* __restrict__ b_in,
    const float* __restrict__ W_edge,
    const float* __restrict__ W_out,
    const int*   __restrict__ src,
    const int*   __restrict__ dst,
    int* __restrict__ cursor,
    int* __restrict__ ework,
    float4* __restrict__ nodeT)
{
    const int tid = threadIdx.x;

    // ---------------- scatter blocks ----------------
    if ((int)blockIdx.x < GS) {
        __shared__ int hist[NBK];
        __shared__ int base[NBK];
        for (int i = tid; i < NBK; i += 256) hist[i] = 0;
        __syncthreads();

        const int4* src4 = (const int4*)src;
        const int4* dst4 = (const int4*)dst;
        const int   b40  = (int)blockIdx.x * EPS4;

        int bb[16], rr[16], pk[16];
        #pragma unroll
        for (int j = 0; j < 4; ++j) {
            const int o4 = j * 256 + tid;
            if (o4 < EPS4) {
                const int4 d4 = dst4[b40 + o4];
                const int4 s4 = src4[b40 + o4];
                const int dv[4] = {d4.x, d4.y, d4.z, d4.w};
                const int sv[4] = {s4.x, s4.y, s4.z, s4.w};
                #pragma unroll
                for (int u = 0; u < 4; ++u) {
                    const int idx = j * 4 + u;
                    const int d = dv[u];
                    const int b = d >> BK_LOG;
                    bb[idx] = b;
                    rr[idx] = atomicAdd(&hist[b], 1);
                    pk[idx] = ((d & (BKW - 1)) << 17) | sv[u];
                }
            }
        }
        __syncthreads();

        for (int b = tid; b < NBK; b += 256) {
            const int c = hist[b];
            if (c) base[b] = atomicAdd(&cursor[b], c);   // one global atomic
        }
        __syncthreads();

        #pragma unroll
        for (int j = 0; j < 4; ++j) {
            const int o4 = j * 256 + tid;
            if (o4 < EPS4) {
                #pragma unroll
                for (int u = 0; u < 4; ++u) {
                    const int idx = j * 4 + u;
                    ework[bb[idx] * CAPB + base[bb[idx]] + rr[idx]] = pk[idx];
                }
            }
        }
        return;
    }

    // ---------------- nodeT blocks ----------------
    __shared__ float sP[64 * 4];   // P[m][j] row-major
    __shared__ float sQ[64 * 4];   // Q[k][j] row-major, 16B rows
    __shared__ float sc[4];

    if (tid < 64) {
        sP[tid * 4 + 0] = W_edge[tid];            // W_u
        sP[tid * 4 + 1] = W_out[tid * 2 + 0];     // W_out[:,0]
        sP[tid * 4 + 2] = W_out[tid * 2 + 1];     // W_out[:,1]
        sP[tid * 4 + 3] = W_edge[64 + tid];       // W_v
    }
    __syncthreads();

    {   // Q[k][j] = sum_m W_in[k][m] * P[m][j]
        const int k = tid >> 2, j = tid & 3;
        float q = 0.f;
        for (int m = 0; m < 64; ++m) q += W_in[k * 64 + m] * sP[m * 4 + j];
        sQ[k * 4 + j] = q;
        if (tid < 4) {
            float cc = 0.f;
            for (int m = 0; m < 64; ++m) cc += b_in[m] * sP[m * 4 + tid];
            sc[tid] = cc;
        }
    }
    __syncthreads();

    const int lane = tid & 63;
    const int wv   = tid >> 6;
    const int n    = ((int)blockIdx.x - GS) * 64 + wv * 16 + (lane >> 2);
    const int ks   = (lane & 3) << 4;                           // 16 k's/lane

    float p0 = 0.f, p1 = 0.f, p2 = 0.f, p3 = 0.f;
    if (n < N_NODES) {
        const float* fr = feat + (size_t)n * 64 + ks;
        #pragma unroll
        for (int i4 = 0; i4 < 4; ++i4) {
            const float4 f = *(const float4*)(fr + i4 * 4);
            const float fv[4] = {f.x, f.y, f.z, f.w};
            #pragma unroll
            for (int u = 0; u < 4; ++u) {
                const float4 q = *(const float4*)&sQ[(ks + i4 * 4 + u) * 4];
                p0 += fv[u] * q.x;
                p1 += fv[u] * q.y;
                p2 += fv[u] * q.z;
                p3 += fv[u] * q.w;
            }
        }
    }
    #pragma unroll
    for (int off = 1; off <= 2; off <<= 1) {
        p0 += __shfl_xor(p0, off);
        p1 += __shfl_xor(p1, off);
        p2 += __shfl_xor(p2, off);
        p3 += __shfl_xor(p3, off);
    }
    if (n < N_NODES && (lane & 3) == 0)
        nodeT[n] = make_float4(p0 + sc[0], p1 + sc[1], p2 + sc[2], p3 + sc[3]);
}

// ---------------------------------------------------------------------------
// K2: unsorted aggregation via LDS fp32 atomics (ds_add_f32 -- per-CU LDS
// unit, NOT the cross-XCD global atomic path). One block (256 thr) per
// 128-node bucket, 782 blocks, 3.5 KB LDS -> high occupancy. Per record:
// gather nodeT[src] (16B, L2-resident), sigmoid, 3 LDS atomic adds
// (m0, m1, count). No rank, no scan, no place -- the sum is commutative.
// Finalize fused: out written straight from the LDS accumulators.
// ---------------------------------------------------------------------------
__global__ __launch_bounds__(256) void agg_kernel(
    const int* __restrict__ ework,
    const int* __restrict__ cursor,
    const float4* __restrict__ nodeT,
    const float* __restrict__ b_edge,
    const float* __restrict__ b_out,
    float2* __restrict__ out)
{
    __shared__ float4 sT[BKW];   // .w pre-biased with b_edge; .y/.z fallback
    __shared__ float  aM0[BKW];
    __shared__ float  aM1[BKW];
    __shared__ int    aC[BKW];

    const int b   = blockIdx.x;
    const int tid = threadIdx.x;

    if (tid < BKW) {
        const int n = b * BKW + tid;
        float4 t = make_float4(0.f, 0.f, 0.f, 0.f);
        if (n < N_NODES) t = nodeT[n];
        t.w += b_edge[0];
        sT[tid] = t;
        aM0[tid] = 0.f;
        aM1[tid] = 0.f;
        aC[tid]  = 0;
    }
    __syncthreads();

    const int cnt = min(cursor[b], CAPB);
    const int4* ew4 = (const int4*)(ework + b * CAPB);   // CAPB*4 % 16 == 0

    #pragma unroll
    for (int j = 0; j < UNS4; ++j) {
        const int o = (j * 256 + tid) * 4;
        if (o < cnt) {
            const int4 v = ew4[j * 256 + tid];
            const int ve[4] = {v.x, v.y, v.z, v.w};
            #pragma unroll
            for (int u = 0; u < 4; ++u) {
                if (o + u < cnt) {
                    const int    l = ve[u] >> 17;
                    const int    s = ve[u] & 0x1FFFF;
                    const float4 t = nodeT[s];
                    const float  w = 1.0f / (1.0f + __expf(-(t.x + sT[l].w)));
                    atomicAdd(&aM0[l], w * t.y);
                    atomicAdd(&aM1[l], w * t.z);
                    atomicAdd(&aC[l], 1);
                }
            }
        }
    }
    __syncthreads();

    if (tid < BKW) {
        const int n = b * BKW + tid;
        if (n < N_NODES) {
            const bool has = aC[tid] > 0;
            out[n] = make_float2((has ? aM0[tid] : sT[tid].y) + b_out[0],
                                 (has ? aM1[tid] : sT[tid].z) + b_out[1]);
        }
    }
}

// ---------------------------------------------------------------------------
extern "C" void kernel_launch(void* const* d_in, const int* in_sizes, int n_in,
                              void* d_out, int out_size, void* d_ws, size_t ws_size,
                              hipStream_t stream) {
    const float* feat   = (const float*)d_in[0];
    const int*   src    = (const int*)d_in[1];
    const int*   dst    = (const int*)d_in[2];
    const float* W_in   = (const float*)d_in[3];
    const float* b_in   = (const float*)d_in[4];
    const float* W_edge = (const float*)d_in[5];
    const float* b_edge = (const float*)d_in[6];
    const float* W_out  = (const float*)d_in[7];
    const float* b_out  = (const float*)d_in[8];
    float2* out = (float2*)d_out;

    // workspace layout (16B-aligned blocks first)
    float4* nodeT  = (float4*)d_ws;                 // 1.6 MB
    int*    ework  = (int*)(nodeT + N_NODES);       // NBK*CAPB ints (8.4 MB)
    int*    cursor = ework + NBK * CAPB;            // NBK ints

    hipMemsetAsync(cursor, 0, NBK * sizeof(int), stream);

    prep_kernel<<<GS + NT_BLOCKS, 256, 0, stream>>>(
        feat, W_in, b_in, W_edge, W_out, src, dst, cursor, ework, nodeT);
    agg_kernel<<<NBK, 256, 0, stream>>>(
        ework, cursor, nodeT, b_edge, b_out, out);
}